// Round 3
// baseline (1013.828 us; speedup 1.0000x reference)
//
#include <hip/hip_runtime.h>

#define N 128
#define NITER 60
#define PSTR 132   // partial-array stride: multiple of 4 floats -> 16B-aligned rows -> b128 LDS ops

// One block per batch row. 256 threads; thread (tr,tc) owns the 8x8 tile
// z[8tr..8tr+7][8tc..8tc+7] and matching w=A tile in registers.
//
// waves_per_eu(2,2): the allocator's default occupancy TARGET (~4-5 waves/EU)
// gave a ~108-reg budget and spilled ~100 live floats to AGPRs -> accvgpr
// shuttles inflated VALU issue 2.1x (R1/R2: VGPR_Count 96/108, VALU-busy
// 616us vs ~285us static). max=2 waves/EU hands the allocator the full
// 256-reg budget; occupancy was already 2 waves/EU so the clamp is free.
__global__ __attribute__((amdgpu_flat_work_group_size(256, 256), amdgpu_waves_per_eu(2, 2)))
void gfusedmax_kernel(const float* __restrict__ x,
                      const float* __restrict__ A,
                      float* __restrict__ out)
{
    const int b   = blockIdx.x;
    const int tid = threadIdx.x;
    const int tr  = tid >> 4;   // 0..15
    const int tc  = tid & 15;   // 0..15
    const int i0  = tr * 8;
    const int j0  = tc * 8;

    __shared__ float rowpart[16 * PSTR];   // [tc][i]
    __shared__ float colpart[16 * PSTR];   // [tr][j]
    __shared__ float yv[N];                // step*y during loop, raw y at end
    __shared__ float sorted[N];
    __shared__ float red[8];

    const float step = 1.0f / 256.0f;   // 1/(2N), exact power of two

    // ---- load w = lam*A (lam=1) tile into registers, init z=0 ----
    float w[8][8];
    float z[8][8];
    const float* Ab = A + (size_t)b * N * N;
    #pragma unroll
    for (int r = 0; r < 8; ++r) {
        const float4* src = (const float4*)(Ab + (size_t)(i0 + r) * N + j0);
        float4 p0 = src[0];
        float4 p1 = src[1];
        w[r][0] = p0.x; w[r][1] = p0.y; w[r][2] = p0.z; w[r][3] = p0.w;
        w[r][4] = p1.x; w[r][5] = p1.y; w[r][6] = p1.z; w[r][7] = p1.w;
        #pragma unroll
        for (int c = 0; c < 8; ++c) z[r][c] = 0.0f;
    }

    float xi = 0.0f;
    if (tid < N) xi = x[(size_t)b * N + tid];

    // partial row/col sums of z, maintained by the fused update loop (z=0 now)
    float pr[8], pc[8];
    #pragma unroll
    for (int r = 0; r < 8; ++r) { pr[r] = 0.0f; pc[r] = 0.0f; }

    float yfin = 0.0f;   // final primal value for tid < 128

    for (int it = 0; it <= NITER; ++it) {
        // (a) publish partial sums (contiguous 8-float runs, 16B-aligned -> b128)
        #pragma unroll
        for (int r = 0; r < 8; ++r) rowpart[tc * PSTR + i0 + r] = pr[r];
        #pragma unroll
        for (int c = 0; c < 8; ++c) colpart[tr * PSTR + j0 + c] = pc[c];
        __syncthreads();

        // (b) threads 0..127 reduce 32 partials, publish step*y (raw y on last)
        if (tid < N) {
            float rs = 0.0f, cs = 0.0f;
            #pragma unroll
            for (int k = 0; k < 16; ++k) rs += rowpart[k * PSTR + tid];
            #pragma unroll
            for (int k = 0; k < 16; ++k) cs += colpart[k * PSTR + tid];
            float y = xi - rs + cs;
            yfin = y;
            // scaling by 2^-8 is exact, so step*yi - step*yj == step*(yi-yj)
            yv[tid] = (it == NITER) ? y : step * y;
        }
        __syncthreads();
        if (it == NITER) break;

        // (c) fused dual update + partial-sum accumulation (5 VALU/element)
        float dr[8], ec[8];
        #pragma unroll
        for (int r = 0; r < 8; ++r) dr[r] = yv[i0 + r];   // contiguous -> b128
        #pragma unroll
        for (int c = 0; c < 8; ++c) ec[c] = yv[j0 + c];
        #pragma unroll
        for (int r = 0; r < 8; ++r) pr[r] = 0.0f;
        #pragma unroll
        for (int c = 0; c < 8; ++c) pc[c] = 0.0f;
        #pragma unroll
        for (int r = 0; r < 8; ++r)
            #pragma unroll
            for (int c = 0; c < 8; ++c) {
                float t = z[r][c] + dr[r] - ec[c];
                float zn = __builtin_amdgcn_fmed3f(t, -w[r][c], w[r][c]);
                z[r][c] = zn;
                pr[r] += zn;
                pc[c] += zn;
            }
    }

    // ---- sparsemax over yv[0..127] (raw y) ----
    float v = yfin;
    if (tid < N) {
        int rk = 0;
        for (int k = 0; k < N; ++k) {
            float u = yv[k];
            rk += (u > v) || (u == v && k < tid);
        }
        sorted[rk] = v;   // rank is a permutation (ties broken by index)
    }
    __syncthreads();

    float s = 0.0f, csum = 0.0f;
    if (tid < N) {
        s = sorted[tid];
        for (int m = 0; m < N; ++m) {            // uniform index -> LDS broadcast
            float t = sorted[m];
            if (m <= tid) csum += t;             // inclusive prefix at sorted pos
        }
    }
    bool mask = (tid < N) && (1.0f + (float)(tid + 1) * s > csum);
    float aRed = mask ? s : 0.0f;
    float bRed = mask ? 1.0f : 0.0f;
    #pragma unroll
    for (int off = 32; off >= 1; off >>= 1) {
        aRed += __shfl_down(aRed, off, 64);
        bRed += __shfl_down(bRed, off, 64);
    }
    const int wid = tid >> 6;
    if ((tid & 63) == 0) { red[wid * 2] = aRed; red[wid * 2 + 1] = bRed; }
    __syncthreads();
    const float tau = (red[0] + red[2] + red[4] + red[6] - 1.0f)
                    / (red[1] + red[3] + red[5] + red[7]);
    if (tid < N) out[(size_t)b * N + tid] = fmaxf(v - tau, 0.0f);
}

extern "C" void kernel_launch(void* const* d_in, const int* in_sizes, int n_in,
                              void* d_out, int out_size, void* d_ws, size_t ws_size,
                              hipStream_t stream) {
    const float* x = (const float*)d_in[0];
    const float* A = (const float*)d_in[1];
    float* out = (float*)d_out;
    const int B = in_sizes[0] / N;   // 4096 rows
    gfusedmax_kernel<<<B, 256, 0, stream>>>(x, A, out);
}

// Round 4
// 874.532 us; speedup vs baseline: 1.1593x; 1.1593x over previous
//
#include <hip/hip_runtime.h>

#define N 128
#define NITER 60
#define PSTR 132   // partial-array stride: multiple of 4 floats -> 16B-aligned rows -> b128 LDS ops

typedef float v2f __attribute__((ext_vector_type(2)));
typedef float v4f __attribute__((ext_vector_type(4)));

// One block per batch row. 256 threads; thread (tr,tc) owns the 8x8 tile
// z[8tr..8tr+7][8tc..8tc+7] and matching w=A tile, held as <2 x float> pairs
// so the update loop compiles to packed-FP32 (v_pk_add_f32: 2 flops/slot,
// CDNA2+). Per element pair: 2 pk (z+dr-ec) + 2 med3 + 1 pk (pr) + 1 pk (pc)
// = 3 VALU slots/element vs 5 scalar.
__global__ __launch_bounds__(256, 1)
void gfusedmax_kernel(const float* __restrict__ x,
                      const float* __restrict__ A,
                      float* __restrict__ out)
{
    const int b   = blockIdx.x;
    const int tid = threadIdx.x;
    const int tr  = tid >> 4;   // 0..15
    const int tc  = tid & 15;   // 0..15
    const int i0  = tr * 8;
    const int j0  = tc * 8;

    __shared__ float rowpart[16 * PSTR];   // [tc][i]
    __shared__ float colpart[16 * PSTR];   // [tr][j]
    __shared__ float yv[N];                // step*y during loop, raw y at end
    __shared__ float sorted[N];
    __shared__ float red[8];

    const float step = 1.0f / 256.0f;   // 1/(2N), exact power of two

    // ---- load w = lam*A (lam=1) tile as pairs, init z=0 ----
    v2f w2[8][4];
    v2f z2[8][4];
    const float* Ab = A + (size_t)b * N * N;
    #pragma unroll
    for (int r = 0; r < 8; ++r) {
        const v4f* src = (const v4f*)(Ab + (size_t)(i0 + r) * N + j0);
        v4f p0 = src[0];
        v4f p1 = src[1];
        w2[r][0] = p0.lo; w2[r][1] = p0.hi;
        w2[r][2] = p1.lo; w2[r][3] = p1.hi;
        #pragma unroll
        for (int cp = 0; cp < 4; ++cp) z2[r][cp] = (v2f)0.0f;
    }

    float xi = 0.0f;
    if (tid < N) xi = x[(size_t)b * N + tid];

    // partial row/col sums of z, maintained by the fused update loop (z=0 now)
    v2f pr2[8], pc2[4];
    #pragma unroll
    for (int r = 0; r < 8; ++r) pr2[r] = (v2f)0.0f;
    #pragma unroll
    for (int cp = 0; cp < 4; ++cp) pc2[cp] = (v2f)0.0f;

    float yfin = 0.0f;   // final primal value for tid < 128

    for (int it = 0; it <= NITER; ++it) {
        // (a) publish partials. pc2 pairs are column-contiguous -> direct
        // pair stores (compiler merges adjacent LDS stores to b128).
        #pragma unroll
        for (int r = 0; r < 8; ++r)
            rowpart[tc * PSTR + i0 + r] = pr2[r].x + pr2[r].y;
        v2f* cp_dst = (v2f*)&colpart[tr * PSTR + j0];
        #pragma unroll
        for (int cp = 0; cp < 4; ++cp) cp_dst[cp] = pc2[cp];
        __syncthreads();

        // (b) threads 0..127 reduce 32 partials, publish step*y (raw y on last)
        if (tid < N) {
            float rs = 0.0f, cs = 0.0f;
            #pragma unroll
            for (int k = 0; k < 16; ++k) rs += rowpart[k * PSTR + tid];
            #pragma unroll
            for (int k = 0; k < 16; ++k) cs += colpart[k * PSTR + tid];
            float y = xi - rs + cs;
            yfin = y;
            // scaling by 2^-8 is exact, so step*yi - step*yj == step*(yi-yj)
            yv[tid] = (it == NITER) ? y : step * y;
        }
        __syncthreads();
        if (it == NITER) break;

        // (c) packed dual update + partial-sum accumulation
        v2f drs[8], ec2[4];
        #pragma unroll
        for (int r = 0; r < 8; ++r) drs[r] = (v2f)yv[i0 + r];   // splat
        const v2f* yv2 = (const v2f*)yv;
        #pragma unroll
        for (int cp = 0; cp < 4; ++cp) ec2[cp] = yv2[tc * 4 + cp];
        #pragma unroll
        for (int r = 0; r < 8; ++r) pr2[r] = (v2f)0.0f;
        #pragma unroll
        for (int cp = 0; cp < 4; ++cp) pc2[cp] = (v2f)0.0f;
        #pragma unroll
        for (int r = 0; r < 8; ++r) {
            #pragma unroll
            for (int cp = 0; cp < 4; ++cp) {
                v2f t  = (z2[r][cp] + drs[r]) - ec2[cp];   // 2x v_pk_add_f32
                v2f wv = w2[r][cp];
                v2f zn;
                zn.x = __builtin_amdgcn_fmed3f(t.x, -wv.x, wv.x);
                zn.y = __builtin_amdgcn_fmed3f(t.y, -wv.y, wv.y);
                z2[r][cp] = zn;
                pr2[r]  += zn;                             // v_pk_add_f32
                pc2[cp] += zn;                             // v_pk_add_f32
            }
        }
    }

    // ---- sparsemax over yv[0..127] (raw y) ----
    float v = yfin;
    if (tid < N) {
        int rk = 0;
        for (int k = 0; k < N; ++k) {
            float u = yv[k];
            rk += (u > v) || (u == v && k < tid);
        }
        sorted[rk] = v;   // rank is a permutation (ties broken by index)
    }
    __syncthreads();

    float s = 0.0f, csum = 0.0f;
    if (tid < N) {
        s = sorted[tid];
        for (int m = 0; m < N; ++m) {            // uniform index -> LDS broadcast
            float t = sorted[m];
            if (m <= tid) csum += t;             // inclusive prefix at sorted pos
        }
    }
    bool mask = (tid < N) && (1.0f + (float)(tid + 1) * s > csum);
    float aRed = mask ? s : 0.0f;
    float bRed = mask ? 1.0f : 0.0f;
    #pragma unroll
    for (int off = 32; off >= 1; off >>= 1) {
        aRed += __shfl_down(aRed, off, 64);
        bRed += __shfl_down(bRed, off, 64);
    }
    const int wid = tid >> 6;
    if ((tid & 63) == 0) { red[wid * 2] = aRed; red[wid * 2 + 1] = bRed; }
    __syncthreads();
    const float tau = (red[0] + red[2] + red[4] + red[6] - 1.0f)
                    / (red[1] + red[3] + red[5] + red[7]);
    if (tid < N) out[(size_t)b * N + tid] = fmaxf(v - tau, 0.0f);
}

extern "C" void kernel_launch(void* const* d_in, const int* in_sizes, int n_in,
                              void* d_out, int out_size, void* d_ws, size_t ws_size,
                              hipStream_t stream) {
    const float* x = (const float*)d_in[0];
    const float* A = (const float*)d_in[1];
    float* out = (float*)d_out;
    const int B = in_sizes[0] / N;   // 4096 rows
    gfusedmax_kernel<<<B, 256, 0, stream>>>(x, A, out);
}